// Round 6
// baseline (339.870 us; speedup 1.0000x reference)
//
#include <hip/hip_runtime.h>

#define W_    256
#define H_    128
#define HW_   32768
#define NB    4
#define NA    5
#define NC    64
#define NIMG  20
#define EPS_  1e-6f

#define TW    32
#define TH    32
#define CAP   3072      // floats per LDS buffer
#define NCH   3         // float4 chunks per thread per channel (256*3*4 = 3072 floats max)

// ---------- bilinear warp taps (matches reference affine_grid + grid_sample) ----------
struct Taps { int o00,o01,o10,o11; float w00,w01,w10,w11; };
struct TapsC { int cy0,cy1,cx0,cx1; float w00,w01,w10,w11; };

__device__ inline TapsC make_taps_c(float M0,float M1,float M2,float M3,float M4,float M5,
                                    int h, int w){
  float gx = 2.0f*((float)w+0.5f)/(float)W_ - 1.0f;
  float gy = 2.0f*((float)h+0.5f)/(float)H_ - 1.0f;
  float X = M0*gx + M1*gy + M2;
  float Y = M3*gx + M4*gy + M5;
  float px = ((X+1.0f)*(float)W_ - 1.0f)*0.5f;
  float py = ((Y+1.0f)*(float)H_ - 1.0f)*0.5f;
  float x0f = floorf(px), y0f = floorf(py);
  float wx1 = px-x0f, wy1 = py-y0f;
  float wx0 = 1.0f-wx1, wy0 = 1.0f-wy1;
  int x0=(int)x0f, y0=(int)y0f, x1=x0+1, y1=y0+1;
  bool vx0=(x0>=0)&&(x0<W_), vx1=(x1>=0)&&(x1<W_);
  bool vy0=(y0>=0)&&(y0<H_), vy1=(y1>=0)&&(y1<H_);
  TapsC t;
  t.cx0=min(max(x0,0),W_-1); t.cx1=min(max(x1,0),W_-1);
  t.cy0=min(max(y0,0),H_-1); t.cy1=min(max(y1,0),H_-1);
  t.w00=(vy0&&vx0)?(wy0*wx0):0.f;
  t.w01=(vy0&&vx1)?(wy0*wx1):0.f;
  t.w10=(vy1&&vx0)?(wy1*wx0):0.f;
  t.w11=(vy1&&vx1)?(wy1*wx1):0.f;
  return t;
}

__device__ inline Taps make_taps(const float* __restrict__ M, int h, int w){
  TapsC c = make_taps_c(M[0],M[1],M[2],M[3],M[4],M[5],h,w);
  Taps t;
  t.o00=c.cy0*W_+c.cx0; t.o01=c.cy0*W_+c.cx1; t.o10=c.cy1*W_+c.cx0; t.o11=c.cy1*W_+c.cx1;
  t.w00=c.w00; t.w01=c.w01; t.w10=c.w10; t.w11=c.w11;
  return t;
}

__device__ inline void proj_pt(float M0,float M1,float M2,float M3,float M4,float M5,
                               int h,int w,float&px,float&py){
  float gx = 2.0f*((float)w+0.5f)/(float)W_ - 1.0f;
  float gy = 2.0f*((float)h+0.5f)/(float)H_ - 1.0f;
  float X = M0*gx + M1*gy + M2;
  float Y = M3*gx + M4*gy + M5;
  px = ((X+1.0f)*(float)W_ - 1.0f)*0.5f;
  py = ((Y+1.0f)*(float)H_ - 1.0f)*0.5f;
}

__device__ inline float clip01(float v){ return fminf(fmaxf(v,0.f),1.f); }
__device__ inline float sigmoidf_(float v){
  if (v>=0.f){ float e=expf(-v); return 1.f/(1.f+e); }
  float e=expf(v); return e/(1.f+e);
}
__device__ inline float quantv(int cnt, float q, float vlo, float vhi){
  if (cnt<=0) return 0.f;
  float pos = q*(float)(cnt-1);
  float frac = pos - floorf(pos);
  return vlo + frac*(vhi-vlo);
}
__device__ inline float ge_f(float t, float lo, float hi){
  return clip01((t-lo)/(hi-lo+EPS_));
}

// ---------- K0: zero counters ----------
__global__ void k_init(int* counters){ if (threadIdx.x < 1+NIMG) counters[threadIdx.x] = 0; }

// ---------- K1: LDS-tiled warp+stats, reg-staged float4 chunks ----------
// Block = 32x32 output tile of one image. Chunk starts aligned to 4-float global
// columns (xs4 = xs&~3) -> every chunk is 16B-aligned AND never crosses a row end.
// Pipeline: load ch c+1 -> regs (dwordx4) | compute ch c from LDS | barrier |
// ds_write_b128 -> other buffer | barrier.  LDS pitch padded to kill bank conflicts.
__global__ __launch_bounds__(256) void k_warp_stats(
  const float* __restrict__ x, const float* __restrict__ psm, const float* __restrict__ nam,
  float* __restrict__ vis, float* __restrict__ scraw, float* __restrict__ sfull,
  float* __restrict__ energy, int* __restrict__ cntv)
{
  __shared__ float smem[2][CAP];
  int tid = threadIdx.x;
  int tx = blockIdx.x, ty = blockIdx.y, bn = blockIdx.z;
  int b = bn/NA, n = bn - b*NA;
  const float* M = nam + (size_t)(b*NA*NA + n)*6;
  float M0=M[0],M1=M[1],M2=M[2],M3=M[3],M4=M[4],M5=M[5];
  int tw0 = tx*TW, th0 = ty*TH;
  int r  = tid>>3;
  int cb = (tid&7)<<2;
  int h  = th0 + r;
  int w0 = tw0 + cb;

  // exact bbox from tile corners (+1 px safety margin)
  float pxa,pya,pxb,pyb,pxc,pyc,pxd,pyd;
  proj_pt(M0,M1,M2,M3,M4,M5, th0,      tw0,      pxa,pya);
  proj_pt(M0,M1,M2,M3,M4,M5, th0,      tw0+TW-1, pxb,pyb);
  proj_pt(M0,M1,M2,M3,M4,M5, th0+TH-1, tw0,      pxc,pyc);
  proj_pt(M0,M1,M2,M3,M4,M5, th0+TH-1, tw0+TW-1, pxd,pyd);
  float pxmin=fminf(fminf(pxa,pxb),fminf(pxc,pxd));
  float pxmax=fmaxf(fmaxf(pxa,pxb),fmaxf(pxc,pxd));
  float pymin=fminf(fminf(pya,pyb),fminf(pyc,pyd));
  float pymax=fmaxf(fmaxf(pya,pyb),fmaxf(pyc,pyd));
  int xs = min(max((int)floorf(pxmin)-1, 0), W_-1);
  int xe = min(max((int)floorf(pxmax)+2, 0), W_-1);
  int ys = min(max((int)floorf(pymin)-1, 0), H_-1);
  int ye = min(max((int)floorf(pymax)+2, 0), H_-1);
  int xs4 = xs & ~3;                      // 16B-aligned origin
  int bwid = xe - xs4 + 1, bh = ye - ys + 1;
  int nck = (bwid+3)>>2;                  // float4 chunks per row
  int bwp = nck<<2;
  int pitch = bwp + 4;                    // pad: never 0 mod 32
  if ((pitch & 31) == 0) pitch += 4;
  int E2 = bh*pitch;

  // per-pixel taps (4 px per thread)
  TapsC tc[4];
  #pragma unroll
  for (int k=0;k<4;++k) tc[k] = make_taps_c(M0,M1,M2,M3,M4,M5, h, w0+k);

  size_t idx = (size_t)bn*HW_ + (size_t)h*W_ + w0;
  float acc[4] = {0.f,0.f,0.f,0.f};

  if (E2 <= CAP){
    int totq = bh*nck;                    // <= CAP/4 = 768 since pitch > bwp
    unsigned magic = (unsigned)((0x100000000ULL + (unsigned)nck - 1) / (unsigned)nck);
    const float* xb0 = x + (size_t)bn*NC*HW_ + (size_t)ys*W_ + xs4;

    // precompute per-thread chunk coords (identical for every channel)
    int qrow[NCH], qcol[NCH];
    #pragma unroll
    for (int k=0;k<NCH;++k){
      int q = tid + (k<<8);
      int qq = min(q, totq-1);
      int row = (int)__umulhi((unsigned)qq, magic);
      qrow[k] = row; qcol[k] = (qq - row*nck)<<2;
    }

    float4 rr[NCH];
    #pragma unroll
    for (int k=0;k<NCH;++k)
      rr[k] = *reinterpret_cast<const float4*>(xb0 + (size_t)qrow[k]*W_ + qcol[k]);

    // psm / vis / sfull / scraw while ch0 loads are in flight
    {
      const float* p0 = psm + ((size_t)bn*2+0)*HW_;
      const float* p1 = psm + ((size_t)bn*2+1)*HW_;
      int vsum = 0;
      #pragma unroll
      for (int k=0;k<4;++k){
        TapsC t = tc[k];
        int o00=t.cy0*W_+t.cx0, o01=t.cy0*W_+t.cx1, o10=t.cy1*W_+t.cx0, o11=t.cy1*W_+t.cx1;
        float vv = t.w00+t.w01+t.w10+t.w11;
        float c0 = t.w00*p0[o00]+t.w01*p0[o01]+t.w10*p0[o10]+t.w11*p0[o11];
        float c1 = t.w00*p1[o00]+t.w01*p1[o01]+t.w10*p1[o10]+t.w11*p1[o11];
        vis[idx+k]   = vv;
        scraw[idx+k] = fmaxf(sigmoidf_(c0), sigmoidf_(c1));
        sfull[idx+k] = (clip01(c0)+clip01(c1))*0.5f;
        vsum += (vv>0.f)?1:0;
      }
      #pragma unroll
      for (int off=32;off;off>>=1) vsum += __shfl_down(vsum,off);
      if ((tid&63)==0) atomicAdd(&cntv[bn], vsum);
    }

    #pragma unroll
    for (int k=0;k<NCH;++k)
      *reinterpret_cast<float4*>(&smem[0][qrow[k]*pitch + qcol[k]]) = rr[k];
    __syncthreads();

    // LDS-local tap offsets
    int li00[4],li01[4],li10[4],li11[4];
    #pragma unroll
    for (int k=0;k<4;++k){
      li00[k]=(tc[k].cy0-ys)*pitch + (tc[k].cx0-xs4);
      li01[k]=(tc[k].cy0-ys)*pitch + (tc[k].cx1-xs4);
      li10[k]=(tc[k].cy1-ys)*pitch + (tc[k].cx0-xs4);
      li11[k]=(tc[k].cy1-ys)*pitch + (tc[k].cx1-xs4);
    }

    #pragma unroll 1
    for (int c=0;c<NC;++c){
      if (c+1 < NC){
        const float* src = xb0 + (size_t)(c+1)*HW_;
        #pragma unroll
        for (int k=0;k<NCH;++k)
          rr[k] = *reinterpret_cast<const float4*>(src + (size_t)qrow[k]*W_ + qcol[k]);
      }
      const float* B = smem[c&1];
      #pragma unroll
      for (int k=0;k<4;++k){
        float v = tc[k].w00*B[li00[k]] + tc[k].w01*B[li01[k]]
                + tc[k].w10*B[li10[k]] + tc[k].w11*B[li11[k]];
        acc[k] += v*v;
      }
      if (c+1 < NC){
        __syncthreads();
        float* Bn = smem[(c+1)&1];
        #pragma unroll
        for (int k=0;k<NCH;++k)
          *reinterpret_cast<float4*>(&Bn[qrow[k]*pitch + qcol[k]]) = rr[k];
        __syncthreads();
      }
    }
  } else {
    // fallback: direct global gather (keeps correctness universal)
    const float* p0 = psm + ((size_t)bn*2+0)*HW_;
    const float* p1 = psm + ((size_t)bn*2+1)*HW_;
    int vsum = 0;
    int go00[4],go01[4],go10[4],go11[4];
    #pragma unroll
    for (int k=0;k<4;++k){
      TapsC t = tc[k];
      go00[k]=t.cy0*W_+t.cx0; go01[k]=t.cy0*W_+t.cx1;
      go10[k]=t.cy1*W_+t.cx0; go11[k]=t.cy1*W_+t.cx1;
      float vv = t.w00+t.w01+t.w10+t.w11;
      float c0 = t.w00*p0[go00[k]]+t.w01*p0[go01[k]]+t.w10*p0[go10[k]]+t.w11*p0[go11[k]];
      float c1 = t.w00*p1[go00[k]]+t.w01*p1[go01[k]]+t.w10*p1[go10[k]]+t.w11*p1[go11[k]];
      vis[idx+k]   = vv;
      scraw[idx+k] = fmaxf(sigmoidf_(c0), sigmoidf_(c1));
      sfull[idx+k] = (clip01(c0)+clip01(c1))*0.5f;
      vsum += (vv>0.f)?1:0;
    }
    #pragma unroll
    for (int off=32;off;off>>=1) vsum += __shfl_down(vsum,off);
    if ((tid&63)==0) atomicAdd(&cntv[bn], vsum);
    const float* xb = x + (size_t)bn*NC*HW_;
    for (int c=0;c<NC;++c){
      const float* pc = xb + (size_t)c*HW_;
      #pragma unroll
      for (int k=0;k<4;++k){
        float v = tc[k].w00*pc[go00[k]] + tc[k].w01*pc[go01[k]]
                + tc[k].w10*pc[go10[k]] + tc[k].w11*pc[go11[k]];
        acc[k] += v*v;
      }
    }
  }
  #pragma unroll
  for (int k=0;k<4;++k) energy[idx+k] = acc[k]*(1.0f/64.0f);
}

// ---------- K3: radix-select, ONE BLOCK PER (image, rank) task ----------
#define OS_T 1024
__global__ __launch_bounds__(1024) void k_select(
    const float* __restrict__ energy, const float* __restrict__ scraw,
    const float* __restrict__ ppre, const float* __restrict__ vis,
    const int* __restrict__ cnts,
    float* __restrict__ statsE, float* __restrict__ statsC, float* __restrict__ statsP,
    int mode)
{
  __shared__ int hist[16*256];
  __shared__ int cum[256];
  __shared__ unsigned s_pre;
  __shared__ int s_rk;
  int tid = threadIdx.x;
  int t = blockIdx.x;

  const float* d; const float* m; float* stats; int img, r, cnt;
  if (mode==0){
    bool isC = (t>=96); int tt = isC ? t-96 : t;
    if (tt<80){ img=tt>>2; r=tt&3; } else { int j=tt-80; img=(j>>2)*NA; r=4+(j&3); }
    d = (isC?scraw:energy) + (size_t)img*HW_;
    m = vis + (size_t)img*HW_;
    stats = isC?statsC:statsE;
    cnt = cnts[img];
  } else {
    img = t>>2; r = t&3;
    d = ppre + (size_t)img*HW_;
    m = vis + (size_t)(img*NA)*HW_;
    stats = statsP;
    cnt = cnts[img*NA];
  }
  int cm1 = cnt>0 ? cnt-1 : 0;
  float p2 = 0.2f*(float)cm1, p8 = 0.8f*(float)cm1;
  int l2=(int)floorf(p2), h2=(int)ceilf(p2), l8=(int)floorf(p8), h8=(int)ceilf(p8);
  int rank;
  switch(r){
    case 0: rank=l2; break;      case 1: rank=h2; break;
    case 2: rank=l8; break;      case 3: rank=h8; break;
    case 4: rank=cm1-l2; break;  case 5: rank=cm1-h2; break;
    case 6: rank=cm1-l8; break;  default: rank=cm1-h8; break;
  }

  unsigned key[32];
  #pragma unroll
  for (int k=0;k<32;++k){
    int i = tid + (k<<10);
    unsigned u = __float_as_uint(d[i]);
    unsigned kk = (u & 0x80000000u) ? ~u : (u|0x80000000u);
    key[k] = (m[i] > 0.f) ? kk : 0xFFFFFFFFu;
  }

  if (tid==0){ s_pre=0u; s_rk=rank; }
  int slice = tid & 15;
  #pragma unroll
  for (int round=0; round<4; ++round){
    const int shift = 24 - 8*round;
    for (int i=tid;i<16*256;i+=OS_T) hist[i]=0;
    __syncthreads();
    unsigned pre = s_pre;
    if (round==0){
      #pragma unroll
      for (int k=0;k<32;++k)
        atomicAdd(&hist[slice*256 + (key[k]>>24)], 1);
    } else {
      #pragma unroll
      for (int k=0;k<32;++k)
        if ((key[k]>>(shift+8)) == pre)
          atomicAdd(&hist[slice*256 + ((key[k]>>shift)&255u)], 1);
    }
    __syncthreads();
    if (tid<256){
      int tt=0;
      #pragma unroll
      for (int s=0;s<16;++s) tt += hist[s*256+tid];
      cum[tid]=tt;
    }
    __syncthreads();
    if (tid<64){
      int c0=cum[4*tid+0],c1=cum[4*tid+1],c2=cum[4*tid+2],c3=cum[4*tid+3];
      int i0=c0, i1=i0+c1, i2=i1+c2, i3=i2+c3;
      int tot=i3, scan=tot;
      #pragma unroll
      for (int off=1;off<64;off<<=1){ int v=__shfl_up(scan,off); if (tid>=off) scan+=v; }
      int base = scan-tot;
      int rk = s_rk; unsigned pr = s_pre;
      int b0=base, b1=base+i0, b2=base+i1, b3=base+i2, e3=base+i3;
      if      (rk>=b0 && rk<b1){ s_pre=(pr<<8)|(unsigned)(4*tid+0); s_rk=rk-b0; }
      else if (rk>=b1 && rk<b2){ s_pre=(pr<<8)|(unsigned)(4*tid+1); s_rk=rk-b1; }
      else if (rk>=b2 && rk<b3){ s_pre=(pr<<8)|(unsigned)(4*tid+2); s_rk=rk-b2; }
      else if (rk>=b3 && rk<e3){ s_pre=(pr<<8)|(unsigned)(4*tid+3); s_rk=rk-b3; }
    }
    __syncthreads();
  }
  if (tid==0){
    unsigned k = s_pre;
    unsigned u = (k & 0x80000000u) ? (k & 0x7FFFFFFFu) : ~k;
    stats[img*16 + 1 + r] = __uint_as_float(u);
    if (r==0) stats[img*16] = (float)cnt;
  }
}

// ---------- K4: per-batch scalar params from order stats ----------
__global__ void k_params(const float* __restrict__ statsE, const float* __restrict__ statsC,
                         float* __restrict__ params){
  int b = threadIdx.x;
  if (b>=NB) return;
  float* pr = params + b*32;
  for (int n=0;n<NA;++n){
    const float* sE = statsE + (size_t)(b*NA+n)*16;
    const float* sC = statsC + (size_t)(b*NA+n)*16;
    int cE=(int)sE[0], cC=(int)sC[0];
    pr[n]    = quantv(cE,0.2f,sE[1],sE[2]);
    pr[5+n]  = quantv(cE,0.8f,sE[3],sE[4]);
    pr[10+n] = quantv(cC,0.2f,sC[1],sC[2]);
    pr[15+n] = quantv(cC,0.8f,sC[3],sC[4]);
  }
  const float* sE0 = statsE + (size_t)(b*NA)*16;
  const float* sC0 = statsC + (size_t)(b*NA)*16;
  float loe=pr[0], hie=pr[5], loc=pr[10], hic=pr[15];
  float de_lo=0.f,de_hi=0.f,ke=0.f, dc_lo=0.f,dc_hi=0.f,kc=0.f;
  int c0=(int)sE0[0];
  if (c0>0){
    int cm1=c0-1;
    float pos2=0.2f*(float)cm1, pos8=0.8f*(float)cm1;
    float f2=pos2-floorf(pos2), f8=pos8-floorf(pos8);
    float a,bb;
    a=1.f-ge_f(sE0[5],loe,hie); bb=1.f-ge_f(sE0[6],loe,hie); de_lo=a+f2*(bb-a);
    a=1.f-ge_f(sE0[7],loe,hie); bb=1.f-ge_f(sE0[8],loe,hie); de_hi=a+f8*(bb-a);
    a=ge_f(sE0[1],loe,hie);     bb=ge_f(sE0[2],loe,hie);     ke  =a+f2*(bb-a);
  }
  int c0c=(int)sC0[0];
  if (c0c>0){
    int cm1=c0c-1;
    float pos2=0.2f*(float)cm1, pos8=0.8f*(float)cm1;
    float f2=pos2-floorf(pos2), f8=pos8-floorf(pos8);
    float a,bb;
    a=1.f-ge_f(sC0[5],loc,hic); bb=1.f-ge_f(sC0[6],loc,hic); dc_lo=a+f2*(bb-a);
    a=1.f-ge_f(sC0[7],loc,hic); bb=1.f-ge_f(sC0[8],loc,hic); dc_hi=a+f8*(bb-a);
    a=ge_f(sC0[1],loc,hic);     bb=ge_f(sC0[2],loc,hic);     kc  =a+f2*(bb-a);
  }
  pr[20]=de_lo; pr[21]=de_hi; pr[22]=dc_lo; pr[23]=dc_hi; pr[24]=ke; pr[25]=kc;
}

// ---------- K5: pattern-gate P (pre-normalization) ----------
__global__ __launch_bounds__(256) void k_ppre(
  const float* __restrict__ vis, const float* __restrict__ scraw,
  const float* __restrict__ energy, const float* __restrict__ params,
  float* __restrict__ ppre)
{
  int w=threadIdx.x, h=blockIdx.x, b=blockIdx.y;
  int p=h*W_+w;
  const float* pr = params + b*32;
  size_t base = (size_t)b*NA*HW_ + p;
  float se[NA], sc[NA], vf[NA];
  #pragma unroll
  for (int n=0;n<NA;++n){
    float vv = vis[base + (size_t)n*HW_];
    float f = (vv>0.f)?1.f:0.f; vf[n]=f;
    se[n] = clip01((energy[base+(size_t)n*HW_]-pr[n])/(pr[5+n]-pr[n]+EPS_))*f;
    sc[n] = clip01((scraw[base+(size_t)n*HW_]-pr[10+n])/(pr[15+n]-pr[10+n]+EPS_))*f;
  }
  float sup = 0.f;
  #pragma unroll
  for (int n=1;n<NA;++n) sup += (0.8f*se[n]+0.2f*sc[n])*vf[n];
  sup *= 0.25f;
  float de = clip01(((1.f-se[0])-pr[20])/(pr[21]-pr[20]+EPS_))*vf[0];
  float dc = clip01(((1.f-sc[0])-pr[22])/(pr[23]-pr[22]+EPS_))*vf[0];
  float D  = (0.7f*de + 0.3f*dc)*vf[0];
  bool ke = (se[0] <= pr[24]) && (vf[0]>0.f);
  bool kc = (sc[0] <= pr[25]) && (vf[0]>0.f);
  float kem = (ke&&kc)?1.f:0.f;
  ppre[(size_t)b*HW_+p] = D*sup*(1.f-kem);
}

// ---------- K6: winner argmax + owner/comm bits ----------
__global__ __launch_bounds__(256) void k_owner(
  const float* __restrict__ vis, const float* __restrict__ scraw,
  const float* __restrict__ sfull, const float* __restrict__ ppre,
  const float* __restrict__ statsP, int* __restrict__ omask)
{
  int w=threadIdx.x,h=blockIdx.x,b=blockIdx.y;
  int p=h*W_+w;
  const float* sP = statsP + b*16;
  int cntP=(int)sP[0];
  float plo = quantv(cntP,0.2f,sP[1],sP[2]);
  float phi = quantv(cntP,0.8f,sP[3],sP[4]);
  size_t base=(size_t)b*NA*HW_+p;
  float vf0 = (vis[base]>0.f)?1.f:0.f;
  float Pf = clip01((ppre[(size_t)b*HW_+p]-plo)/(phi-plo+EPS_))*vf0;
  float gate = 0.1f + 0.9f*Pf;
  int winner=0; float best=-1.f;
  int cbits=0;
  #pragma unroll
  for (int n=0;n<NA;++n){
    float vv = vis[base+(size_t)n*HW_];
    float f=(vv>0.f)?1.f:0.f;
    float s = ((sfull[base+(size_t)n*HW_]*f)*gate)*f;
    if (s>best){best=s;winner=n;}
    bool cm = (n==0) || (scraw[base+(size_t)n*HW_] > 0.5f);
    if (cm) cbits |= 1<<n;
  }
  int ob = ((cbits>>winner)&1) ? (1<<winner) : 0;
  omask[(size_t)b*HW_+p] = ob | (cbits<<8);
}

// ---------- K7: 3x3 dilation, final mask, effective-rate count ----------
__global__ __launch_bounds__(256) void k_final(
  const int* __restrict__ omask, int* __restrict__ fmask, int* __restrict__ counter)
{
  int w=threadIdx.x,h=blockIdx.x,b=blockIdx.y;
  int p=h*W_+w;
  const int* om = omask + (size_t)b*HW_;
  int ow=0;
  #pragma unroll
  for (int dy=-1;dy<=1;++dy){
    int y=h+dy; if (y<0||y>=H_) continue;
    #pragma unroll
    for (int dx=-1;dx<=1;++dx){
      int x=w+dx; if (x<0||x>=W_) continue;
      ow |= om[y*W_+x];
    }
  }
  int cbits=(om[p]>>8)&31;
  int fin = ow & cbits & 31;
  fmask[(size_t)b*HW_+p]=fin;
  int cn = __popc(fin & 30);
  for (int off=32;off;off>>=1) cn += __shfl_down(cn,off);
  if ((threadIdx.x&63)==0) atomicAdd(counter, cn);
}

// ---------- K8: masked-max warped output + effective rate ----------
__global__ __launch_bounds__(256, 2) void k_out(
  const float* __restrict__ x, const float* __restrict__ nam,
  const int* __restrict__ fmask, const int* __restrict__ counter,
  float* __restrict__ out, int out_size)
{
  int w=threadIdx.x, h=blockIdx.x, b=blockIdx.y;
  int p=h*W_+w;
  int fin = fmask[(size_t)b*HW_+p] & 31;
  float init = (__popc(fin)<NA) ? 0.f : -__builtin_inff();
  Taps tp[NA];
  #pragma unroll
  for (int n=0;n<NA;++n) tp[n] = make_taps(nam + (size_t)(b*NA*NA+n)*6, h, w);
  #pragma unroll 1
  for (int cb=0; cb<NC/16; ++cb){
    float m[16];
    #pragma unroll
    for (int c=0;c<16;++c) m[c]=init;
    #pragma unroll
    for (int n=0;n<NA;++n){
      if (!((fin>>n)&1)) continue;
      const float* pc = x + ((size_t)(b*NA+n)*NC + cb*16)*HW_;
      float a00[16],a01[16],a10[16],a11[16];
      #pragma unroll
      for (int c=0;c<16;++c){
        a00[c]=pc[tp[n].o00]; a01[c]=pc[tp[n].o01]; a10[c]=pc[tp[n].o10]; a11[c]=pc[tp[n].o11];
        pc += HW_;
      }
      #pragma unroll
      for (int c=0;c<16;++c){
        float v = tp[n].w00*a00[c] + tp[n].w01*a01[c] + tp[n].w10*a10[c] + tp[n].w11*a11[c];
        m[c] = fmaxf(m[c], v);
      }
    }
    #pragma unroll
    for (int c=0;c<16;++c)
      out[(((size_t)b*NC + cb*16 + c)*H_+h)*W_+w] = m[c];
  }
  if (b==0 && h==0 && w==0)
    out[out_size-1] = (float)(*counter) * (1.0f/524288.0f);  // /(B*(N-1)*H*W)
}

extern "C" void kernel_launch(void* const* d_in, const int* in_sizes, int n_in,
                              void* d_out, int out_size, void* d_ws, size_t ws_size,
                              hipStream_t stream) {
  (void)in_sizes; (void)n_in; (void)ws_size;
  const float* x   = (const float*)d_in[0];
  const float* psm = (const float*)d_in[1];
  const float* nam = (const float*)d_in[3];
  float* out = (float*)d_out;

  float* ws     = (float*)d_ws;
  float* vis    = ws;                         // 20*HW
  float* scraw  = vis    + (size_t)NIMG*HW_;  // 20*HW
  float* sfull  = scraw  + (size_t)NIMG*HW_;  // 20*HW
  float* energy = sfull  + (size_t)NIMG*HW_;  // 20*HW
  float* ppre   = energy + (size_t)NIMG*HW_;  // 4*HW
  float* statsE = ppre   + (size_t)NB*HW_;    // 20*16
  float* statsC = statsE + NIMG*16;           // 20*16
  float* statsP = statsC + NIMG*16;           // 4*16
  float* params = statsP + NB*16;             // 4*32
  int*   omask  = (int*)(params + NB*32);     // 4*HW
  int*   fmask  = omask + (size_t)NB*HW_;     // 4*HW
  int*   counter= fmask + (size_t)NB*HW_;     // 1 (+ NIMG vis-counts)
  int*   cntv   = counter + 1;                // 20

  hipLaunchKernelGGL(k_init, dim3(1), dim3(64), 0, stream, counter);
  hipLaunchKernelGGL(k_warp_stats, dim3(W_/TW, H_/TH, NIMG), dim3(256), 0, stream,
                     x, psm, nam, vis, scraw, sfull, energy, cntv);
  hipLaunchKernelGGL(k_select, dim3(192), dim3(OS_T), 0, stream,
                     energy, scraw, ppre, vis, cntv, statsE, statsC, statsP, 0);
  hipLaunchKernelGGL(k_params, dim3(1), dim3(64), 0, stream, statsE, statsC, params);
  hipLaunchKernelGGL(k_ppre, dim3(H_,NB), dim3(W_), 0, stream,
                     vis, scraw, energy, params, ppre);
  hipLaunchKernelGGL(k_select, dim3(16), dim3(OS_T), 0, stream,
                     energy, scraw, ppre, vis, cntv, statsE, statsC, statsP, 1);
  hipLaunchKernelGGL(k_owner, dim3(H_,NB), dim3(W_), 0, stream,
                     vis, scraw, sfull, ppre, statsP, omask);
  hipLaunchKernelGGL(k_final, dim3(H_,NB), dim3(W_), 0, stream, omask, fmask, counter);
  hipLaunchKernelGGL(k_out, dim3(H_,NB), dim3(W_), 0, stream,
                     x, nam, fmask, counter, out, out_size);
}

// Round 7
// 238.271 us; speedup vs baseline: 1.4264x; 1.4264x over previous
//
#include <hip/hip_runtime.h>

#define W_    256
#define H_    128
#define HW_   32768
#define NB    4
#define NA    5
#define NC    64
#define NIMG  20
#define EPS_  1e-6f

#define TW    32
#define TH    32
#define CAP   3072      // floats per LDS buffer
#define TRIPS 3         // global_load_lds(16B) trips per channel: 3*256 lanes*4 floats = 3072

// ---------- bilinear warp taps (matches reference affine_grid + grid_sample) ----------
struct Taps { int o00,o01,o10,o11; float w00,w01,w10,w11; };
struct TapsC { int cy0,cy1,cx0,cx1; float w00,w01,w10,w11; };

__device__ inline TapsC make_taps_c(float M0,float M1,float M2,float M3,float M4,float M5,
                                    int h, int w){
  float gx = 2.0f*((float)w+0.5f)/(float)W_ - 1.0f;
  float gy = 2.0f*((float)h+0.5f)/(float)H_ - 1.0f;
  float X = M0*gx + M1*gy + M2;
  float Y = M3*gx + M4*gy + M5;
  float px = ((X+1.0f)*(float)W_ - 1.0f)*0.5f;
  float py = ((Y+1.0f)*(float)H_ - 1.0f)*0.5f;
  float x0f = floorf(px), y0f = floorf(py);
  float wx1 = px-x0f, wy1 = py-y0f;
  float wx0 = 1.0f-wx1, wy0 = 1.0f-wy1;
  int x0=(int)x0f, y0=(int)y0f, x1=x0+1, y1=y0+1;
  bool vx0=(x0>=0)&&(x0<W_), vx1=(x1>=0)&&(x1<W_);
  bool vy0=(y0>=0)&&(y0<H_), vy1=(y1>=0)&&(y1<H_);
  TapsC t;
  t.cx0=min(max(x0,0),W_-1); t.cx1=min(max(x1,0),W_-1);
  t.cy0=min(max(y0,0),H_-1); t.cy1=min(max(y1,0),H_-1);
  t.w00=(vy0&&vx0)?(wy0*wx0):0.f;
  t.w01=(vy0&&vx1)?(wy0*wx1):0.f;
  t.w10=(vy1&&vx0)?(wy1*wx0):0.f;
  t.w11=(vy1&&vx1)?(wy1*wx1):0.f;
  return t;
}

__device__ inline Taps make_taps(const float* __restrict__ M, int h, int w){
  TapsC c = make_taps_c(M[0],M[1],M[2],M[3],M[4],M[5],h,w);
  Taps t;
  t.o00=c.cy0*W_+c.cx0; t.o01=c.cy0*W_+c.cx1; t.o10=c.cy1*W_+c.cx0; t.o11=c.cy1*W_+c.cx1;
  t.w00=c.w00; t.w01=c.w01; t.w10=c.w10; t.w11=c.w11;
  return t;
}

__device__ inline void proj_pt(float M0,float M1,float M2,float M3,float M4,float M5,
                               int h,int w,float&px,float&py){
  float gx = 2.0f*((float)w+0.5f)/(float)W_ - 1.0f;
  float gy = 2.0f*((float)h+0.5f)/(float)H_ - 1.0f;
  float X = M0*gx + M1*gy + M2;
  float Y = M3*gx + M4*gy + M5;
  px = ((X+1.0f)*(float)W_ - 1.0f)*0.5f;
  py = ((Y+1.0f)*(float)H_ - 1.0f)*0.5f;
}

__device__ inline float clip01(float v){ return fminf(fmaxf(v,0.f),1.f); }
__device__ inline float sigmoidf_(float v){
  if (v>=0.f){ float e=expf(-v); return 1.f/(1.f+e); }
  float e=expf(v); return e/(1.f+e);
}
__device__ inline float quantv(int cnt, float q, float vlo, float vhi){
  if (cnt<=0) return 0.f;
  float pos = q*(float)(cnt-1);
  float frac = pos - floorf(pos);
  return vlo + frac*(vhi-vlo);
}
__device__ inline float ge_f(float t, float lo, float hi){
  return clip01((t-lo)/(hi-lo+EPS_));
}

#define SBAR __builtin_amdgcn_sched_barrier(0)

// ---------- K0: zero counters ----------
__global__ void k_init(int* counters){ if (threadIdx.x < 1+NIMG) counters[threadIdx.x] = 0; }

// ---------- K1: LDS-tiled warp+stats via width-16 global_load_lds ----------
// Block = 32x32 output tile. Per channel the bbox (linear [bh][bwp] layout,
// bwp = 4-aligned width) streams into LDS with 3 global_load_lds_dwordx4 per
// thread, double-buffered with counted vmcnt(3). Interp reads fused x-pairs
// B[a], B[a+1] with edge-exact remapped weights (bit-identical to clamped gather).
__global__ __launch_bounds__(256) void k_warp_stats(
  const float* __restrict__ x, const float* __restrict__ psm, const float* __restrict__ nam,
  float* __restrict__ vis, float* __restrict__ scraw, float* __restrict__ sfull,
  float* __restrict__ energy, int* __restrict__ cntv)
{
  __shared__ __align__(16) float smem[2][CAP];
  int tid = threadIdx.x;
  int tx = blockIdx.x, ty = blockIdx.y, bn = blockIdx.z;
  int b = bn/NA, n = bn - b*NA;
  const float* M = nam + (size_t)(b*NA*NA + n)*6;
  float M0=M[0],M1=M[1],M2=M[2],M3=M[3],M4=M[4],M5=M[5];
  int tw0 = tx*TW, th0 = ty*TH;
  int r  = tid>>3;
  int cb = (tid&7)<<2;
  int h  = th0 + r;
  int w0 = tw0 + cb;

  // exact bbox from tile corners (+1 px safety margin)
  float pxa,pya,pxb,pyb,pxc,pyc,pxd,pyd;
  proj_pt(M0,M1,M2,M3,M4,M5, th0,      tw0,      pxa,pya);
  proj_pt(M0,M1,M2,M3,M4,M5, th0,      tw0+TW-1, pxb,pyb);
  proj_pt(M0,M1,M2,M3,M4,M5, th0+TH-1, tw0,      pxc,pyc);
  proj_pt(M0,M1,M2,M3,M4,M5, th0+TH-1, tw0+TW-1, pxd,pyd);
  float pxmin=fminf(fminf(pxa,pxb),fminf(pxc,pxd));
  float pxmax=fmaxf(fmaxf(pxa,pxb),fmaxf(pxc,pxd));
  float pymin=fminf(fminf(pya,pyb),fminf(pyc,pyd));
  float pymax=fmaxf(fmaxf(pya,pyb),fmaxf(pyc,pyd));
  int xs = min(max((int)floorf(pxmin)-1, 0), W_-1);
  int xe = min(max((int)floorf(pxmax)+2, 0), W_-1);
  int ys = min(max((int)floorf(pymin)-1, 0), H_-1);
  int ye = min(max((int)floorf(pymax)+2, 0), H_-1);
  int xs4 = xs & ~3;                      // 16B-aligned origin (xs4 <= W-4 always)
  int bwid = xe - xs4 + 1, bh = ye - ys + 1;
  int nck = (bwid+3)>>2;                  // float4 chunks per row
  int bwp = nck<<2;                       // linear LDS pitch (no pad: gload_lds dest)
  int E2 = bh*bwp;
  bool ok = (E2 <= CAP);

  // ---- per-pixel taps: full info (validity flags needed for fused pairs) ----
  float vvv[4], w00_[4],w01_[4],w10_[4],w11_[4];
  int   gx0[4],gx1[4],gy0c[4],gy1c[4];   // clamped coords (psm gather + fallback)
  int   rx0[4]; bool vx0f[4];
  #pragma unroll
  for (int k=0;k<4;++k){
    float px,py; proj_pt(M0,M1,M2,M3,M4,M5, h, w0+k, px,py);
    float x0f=floorf(px), y0f=floorf(py);
    float wx1=px-x0f, wx0=1.f-wx1, wy1=py-y0f, wy0=1.f-wy1;
    int x0=(int)x0f, y0=(int)y0f, x1=x0+1, y1=y0+1;
    bool vx0=(x0>=0)&&(x0<W_), vx1=(x1>=0)&&(x1<W_);
    bool vy0=(y0>=0)&&(y0<H_), vy1=(y1>=0)&&(y1<H_);
    float w00=(vy0&&vx0)?(wy0*wx0):0.f;
    float w01=(vy0&&vx1)?(wy0*wx1):0.f;
    float w10=(vy1&&vx0)?(wy1*wx0):0.f;
    float w11=(vy1&&vx1)?(wy1*wx1):0.f;
    w00_[k]=w00; w01_[k]=w01; w10_[k]=w10; w11_[k]=w11;
    vvv[k]=w00+w01+w10+w11;
    gx0[k]=min(max(x0,0),W_-1); gx1[k]=min(max(x1,0),W_-1);
    gy0c[k]=min(max(y0,0),H_-1); gy1c[k]=min(max(y1,0),H_-1);
    rx0[k]=x0; vx0f[k]=vx0;
  }

  size_t idx = (size_t)bn*HW_ + (size_t)h*W_ + w0;
  float acc[4] = {0.f,0.f,0.f,0.f};

  // ---- issue first two channels before the psm block (overlap) ----
  int srcoff[TRIPS]; int ldsbase = (tid>>6)<<6;   // wave-uniform chunk base
  const float* xb0 = x + (size_t)bn*NC*HW_ + (size_t)ys*W_ + xs4;
  if (ok){
    int totq = bh*nck;
    unsigned magic = (unsigned)((0x100000000ULL + (unsigned)nck - 1) / (unsigned)nck);
    int colcap = (W_-4) - xs4;
    #pragma unroll
    for (int k=0;k<TRIPS;++k){
      int qq = min(tid + (k<<8), totq-1);
      int row = (int)__umulhi((unsigned)qq, magic);
      int col = (qq - row*nck)<<2;
      srcoff[k] = row*W_ + min(col, colcap);   // clamped: never reads past row/alloc
    }
  }
  auto issue = [&](int ch, int bsel){
    const float* src = xb0 + (size_t)ch*HW_;
    #pragma unroll
    for (int k=0;k<TRIPS;++k){
      __builtin_amdgcn_global_load_lds(
        (const __attribute__((address_space(1))) void*)(src + srcoff[k]),
        (__attribute__((address_space(3))) void*)&smem[bsel][(ldsbase + (k<<8))<<2],
        16, 0, 0);
    }
  };
  if (ok){ issue(0,0); issue(1,1); }

  // ---- psm / vis / sfull / scraw (global gather; overlaps staging) ----
  {
    const float* p0 = psm + ((size_t)bn*2+0)*HW_;
    const float* p1 = psm + ((size_t)bn*2+1)*HW_;
    int vsum = 0;
    #pragma unroll
    for (int k=0;k<4;++k){
      int o00=gy0c[k]*W_+gx0[k], o01=gy0c[k]*W_+gx1[k];
      int o10=gy1c[k]*W_+gx0[k], o11=gy1c[k]*W_+gx1[k];
      float c0 = w00_[k]*p0[o00]+w01_[k]*p0[o01]+w10_[k]*p0[o10]+w11_[k]*p0[o11];
      float c1 = w00_[k]*p1[o00]+w01_[k]*p1[o01]+w10_[k]*p1[o10]+w11_[k]*p1[o11];
      vis[idx+k]   = vvv[k];
      scraw[idx+k] = fmaxf(sigmoidf_(c0), sigmoidf_(c1));
      sfull[idx+k] = (clip01(c0)+clip01(c1))*0.5f;
      vsum += (vvv[k]>0.f)?1:0;
    }
    #pragma unroll
    for (int off=32;off;off>>=1) vsum += __shfl_down(vsum,off);
    if ((tid&63)==0) atomicAdd(&cntv[bn], vsum);
  }

  if (ok){
    // fused-pair LDS offsets + edge-exact remapped weights:
    //  pair base bc = clamp(x0-xs4); e0=vx0?w00:w01 reads bc, e1=vx0?w01:0 reads bc+1.
    //  All nonzero-weight reads hit valid image data; zero-weight reads are finite.
    int a0[4],a1[4]; float e0[4],e1[4],f0[4],f1[4];
    #pragma unroll
    for (int k=0;k<4;++k){
      int bc = min(max(rx0[k]-xs4,0), bwp-1);
      a0[k] = (gy0c[k]-ys)*bwp + bc;
      a1[k] = (gy1c[k]-ys)*bwp + bc;
      bool v0 = vx0f[k];
      e0[k] = v0 ? w00_[k] : w01_[k];
      e1[k] = v0 ? w01_[k] : 0.f;
      f0[k] = v0 ? w10_[k] : w11_[k];
      f1[k] = v0 ? w11_[k] : 0.f;
    }
    #pragma unroll 1
    for (int c=0;c<NC;++c){
      asm volatile("s_waitcnt vmcnt(3)" ::: "memory"); SBAR;   // TRIPS newest may fly
      __builtin_amdgcn_s_barrier(); SBAR;
      const float* B = smem[c&1];
      #pragma unroll
      for (int k=0;k<4;++k){
        float r00=B[a0[k]], r01=B[a0[k]+1];
        float r10=B[a1[k]], r11=B[a1[k]+1];
        float v = e0[k]*r00 + e1[k]*r01 + f0[k]*r10 + f1[k]*r11;
        acc[k] += v*v;
      }
      asm volatile("s_waitcnt lgkmcnt(0)" ::: "memory"); SBAR;
      __builtin_amdgcn_s_barrier(); SBAR;
      issue(min(c+2,NC-1), c&1);    // dummy re-issue at tail keeps vmcnt math uniform
    }
    asm volatile("s_waitcnt vmcnt(0)" ::: "memory");
  } else {
    // fallback: direct global gather (correctness-universal)
    const float* xb = x + (size_t)bn*NC*HW_;
    int go00[4],go01[4],go10[4],go11[4];
    #pragma unroll
    for (int k=0;k<4;++k){
      go00[k]=gy0c[k]*W_+gx0[k]; go01[k]=gy0c[k]*W_+gx1[k];
      go10[k]=gy1c[k]*W_+gx0[k]; go11[k]=gy1c[k]*W_+gx1[k];
    }
    for (int c=0;c<NC;++c){
      const float* pc = xb + (size_t)c*HW_;
      #pragma unroll
      for (int k=0;k<4;++k){
        float v = w00_[k]*pc[go00[k]] + w01_[k]*pc[go01[k]]
                + w10_[k]*pc[go10[k]] + w11_[k]*pc[go11[k]];
        acc[k] += v*v;
      }
    }
  }
  #pragma unroll
  for (int k=0;k<4;++k) energy[idx+k] = acc[k]*(1.0f/64.0f);
}

// ---------- K3: radix-select, ONE BLOCK PER (image, rank) task ----------
#define OS_T 1024
__global__ __launch_bounds__(1024) void k_select(
    const float* __restrict__ energy, const float* __restrict__ scraw,
    const float* __restrict__ ppre, const float* __restrict__ vis,
    const int* __restrict__ cnts,
    float* __restrict__ statsE, float* __restrict__ statsC, float* __restrict__ statsP,
    int mode)
{
  __shared__ int hist[16*256];
  __shared__ int cum[256];
  __shared__ unsigned s_pre;
  __shared__ int s_rk;
  int tid = threadIdx.x;
  int t = blockIdx.x;

  const float* d; const float* m; float* stats; int img, r, cnt;
  if (mode==0){
    bool isC = (t>=96); int tt = isC ? t-96 : t;
    if (tt<80){ img=tt>>2; r=tt&3; } else { int j=tt-80; img=(j>>2)*NA; r=4+(j&3); }
    d = (isC?scraw:energy) + (size_t)img*HW_;
    m = vis + (size_t)img*HW_;
    stats = isC?statsC:statsE;
    cnt = cnts[img];
  } else {
    img = t>>2; r = t&3;
    d = ppre + (size_t)img*HW_;
    m = vis + (size_t)(img*NA)*HW_;
    stats = statsP;
    cnt = cnts[img*NA];
  }
  int cm1 = cnt>0 ? cnt-1 : 0;
  float p2 = 0.2f*(float)cm1, p8 = 0.8f*(float)cm1;
  int l2=(int)floorf(p2), h2=(int)ceilf(p2), l8=(int)floorf(p8), h8=(int)ceilf(p8);
  int rank;
  switch(r){
    case 0: rank=l2; break;      case 1: rank=h2; break;
    case 2: rank=l8; break;      case 3: rank=h8; break;
    case 4: rank=cm1-l2; break;  case 5: rank=cm1-h2; break;
    case 6: rank=cm1-l8; break;  default: rank=cm1-h8; break;
  }

  unsigned key[32];
  #pragma unroll
  for (int k=0;k<32;++k){
    int i = tid + (k<<10);
    unsigned u = __float_as_uint(d[i]);
    unsigned kk = (u & 0x80000000u) ? ~u : (u|0x80000000u);
    key[k] = (m[i] > 0.f) ? kk : 0xFFFFFFFFu;
  }

  if (tid==0){ s_pre=0u; s_rk=rank; }
  int slice = tid & 15;
  #pragma unroll
  for (int round=0; round<4; ++round){
    const int shift = 24 - 8*round;
    for (int i=tid;i<16*256;i+=OS_T) hist[i]=0;
    __syncthreads();
    unsigned pre = s_pre;
    if (round==0){
      #pragma unroll
      for (int k=0;k<32;++k)
        atomicAdd(&hist[slice*256 + (key[k]>>24)], 1);
    } else {
      #pragma unroll
      for (int k=0;k<32;++k)
        if ((key[k]>>(shift+8)) == pre)
          atomicAdd(&hist[slice*256 + ((key[k]>>shift)&255u)], 1);
    }
    __syncthreads();
    if (tid<256){
      int tt=0;
      #pragma unroll
      for (int s=0;s<16;++s) tt += hist[s*256+tid];
      cum[tid]=tt;
    }
    __syncthreads();
    if (tid<64){
      int c0=cum[4*tid+0],c1=cum[4*tid+1],c2=cum[4*tid+2],c3=cum[4*tid+3];
      int i0=c0, i1=i0+c1, i2=i1+c2, i3=i2+c3;
      int tot=i3, scan=tot;
      #pragma unroll
      for (int off=1;off<64;off<<=1){ int v=__shfl_up(scan,off); if (tid>=off) scan+=v; }
      int base = scan-tot;
      int rk = s_rk; unsigned pr = s_pre;
      int b0=base, b1=base+i0, b2=base+i1, b3=base+i2, e3=base+i3;
      if      (rk>=b0 && rk<b1){ s_pre=(pr<<8)|(unsigned)(4*tid+0); s_rk=rk-b0; }
      else if (rk>=b1 && rk<b2){ s_pre=(pr<<8)|(unsigned)(4*tid+1); s_rk=rk-b1; }
      else if (rk>=b2 && rk<b3){ s_pre=(pr<<8)|(unsigned)(4*tid+2); s_rk=rk-b2; }
      else if (rk>=b3 && rk<e3){ s_pre=(pr<<8)|(unsigned)(4*tid+3); s_rk=rk-b3; }
    }
    __syncthreads();
  }
  if (tid==0){
    unsigned k = s_pre;
    unsigned u = (k & 0x80000000u) ? (k & 0x7FFFFFFFu) : ~k;
    stats[img*16 + 1 + r] = __uint_as_float(u);
    if (r==0) stats[img*16] = (float)cnt;
  }
}

// ---------- K4: per-batch scalar params from order stats ----------
__global__ void k_params(const float* __restrict__ statsE, const float* __restrict__ statsC,
                         float* __restrict__ params){
  int b = threadIdx.x;
  if (b>=NB) return;
  float* pr = params + b*32;
  for (int n=0;n<NA;++n){
    const float* sE = statsE + (size_t)(b*NA+n)*16;
    const float* sC = statsC + (size_t)(b*NA+n)*16;
    int cE=(int)sE[0], cC=(int)sC[0];
    pr[n]    = quantv(cE,0.2f,sE[1],sE[2]);
    pr[5+n]  = quantv(cE,0.8f,sE[3],sE[4]);
    pr[10+n] = quantv(cC,0.2f,sC[1],sC[2]);
    pr[15+n] = quantv(cC,0.8f,sC[3],sC[4]);
  }
  const float* sE0 = statsE + (size_t)(b*NA)*16;
  const float* sC0 = statsC + (size_t)(b*NA)*16;
  float loe=pr[0], hie=pr[5], loc=pr[10], hic=pr[15];
  float de_lo=0.f,de_hi=0.f,ke=0.f, dc_lo=0.f,dc_hi=0.f,kc=0.f;
  int c0=(int)sE0[0];
  if (c0>0){
    int cm1=c0-1;
    float pos2=0.2f*(float)cm1, pos8=0.8f*(float)cm1;
    float f2=pos2-floorf(pos2), f8=pos8-floorf(pos8);
    float a,bb;
    a=1.f-ge_f(sE0[5],loe,hie); bb=1.f-ge_f(sE0[6],loe,hie); de_lo=a+f2*(bb-a);
    a=1.f-ge_f(sE0[7],loe,hie); bb=1.f-ge_f(sE0[8],loe,hie); de_hi=a+f8*(bb-a);
    a=ge_f(sE0[1],loe,hie);     bb=ge_f(sE0[2],loe,hie);     ke  =a+f2*(bb-a);
  }
  int c0c=(int)sC0[0];
  if (c0c>0){
    int cm1=c0c-1;
    float pos2=0.2f*(float)cm1, pos8=0.8f*(float)cm1;
    float f2=pos2-floorf(pos2), f8=pos8-floorf(pos8);
    float a,bb;
    a=1.f-ge_f(sC0[5],loc,hic); bb=1.f-ge_f(sC0[6],loc,hic); dc_lo=a+f2*(bb-a);
    a=1.f-ge_f(sC0[7],loc,hic); bb=1.f-ge_f(sC0[8],loc,hic); dc_hi=a+f8*(bb-a);
    a=ge_f(sC0[1],loc,hic);     bb=ge_f(sC0[2],loc,hic);     kc  =a+f2*(bb-a);
  }
  pr[20]=de_lo; pr[21]=de_hi; pr[22]=dc_lo; pr[23]=dc_hi; pr[24]=ke; pr[25]=kc;
}

// ---------- K5: pattern-gate P (pre-normalization) ----------
__global__ __launch_bounds__(256) void k_ppre(
  const float* __restrict__ vis, const float* __restrict__ scraw,
  const float* __restrict__ energy, const float* __restrict__ params,
  float* __restrict__ ppre)
{
  int w=threadIdx.x, h=blockIdx.x, b=blockIdx.y;
  int p=h*W_+w;
  const float* pr = params + b*32;
  size_t base = (size_t)b*NA*HW_ + p;
  float se[NA], sc[NA], vf[NA];
  #pragma unroll
  for (int n=0;n<NA;++n){
    float vv = vis[base + (size_t)n*HW_];
    float f = (vv>0.f)?1.f:0.f; vf[n]=f;
    se[n] = clip01((energy[base+(size_t)n*HW_]-pr[n])/(pr[5+n]-pr[n]+EPS_))*f;
    sc[n] = clip01((scraw[base+(size_t)n*HW_]-pr[10+n])/(pr[15+n]-pr[10+n]+EPS_))*f;
  }
  float sup = 0.f;
  #pragma unroll
  for (int n=1;n<NA;++n) sup += (0.8f*se[n]+0.2f*sc[n])*vf[n];
  sup *= 0.25f;
  float de = clip01(((1.f-se[0])-pr[20])/(pr[21]-pr[20]+EPS_))*vf[0];
  float dc = clip01(((1.f-sc[0])-pr[22])/(pr[23]-pr[22]+EPS_))*vf[0];
  float D  = (0.7f*de + 0.3f*dc)*vf[0];
  bool ke = (se[0] <= pr[24]) && (vf[0]>0.f);
  bool kc = (sc[0] <= pr[25]) && (vf[0]>0.f);
  float kem = (ke&&kc)?1.f:0.f;
  ppre[(size_t)b*HW_+p] = D*sup*(1.f-kem);
}

// ---------- K6: winner argmax + owner/comm bits ----------
__global__ __launch_bounds__(256) void k_owner(
  const float* __restrict__ vis, const float* __restrict__ scraw,
  const float* __restrict__ sfull, const float* __restrict__ ppre,
  const float* __restrict__ statsP, int* __restrict__ omask)
{
  int w=threadIdx.x,h=blockIdx.x,b=blockIdx.y;
  int p=h*W_+w;
  const float* sP = statsP + b*16;
  int cntP=(int)sP[0];
  float plo = quantv(cntP,0.2f,sP[1],sP[2]);
  float phi = quantv(cntP,0.8f,sP[3],sP[4]);
  size_t base=(size_t)b*NA*HW_+p;
  float vf0 = (vis[base]>0.f)?1.f:0.f;
  float Pf = clip01((ppre[(size_t)b*HW_+p]-plo)/(phi-plo+EPS_))*vf0;
  float gate = 0.1f + 0.9f*Pf;
  int winner=0; float best=-1.f;
  int cbits=0;
  #pragma unroll
  for (int n=0;n<NA;++n){
    float vv = vis[base+(size_t)n*HW_];
    float f=(vv>0.f)?1.f:0.f;
    float s = ((sfull[base+(size_t)n*HW_]*f)*gate)*f;
    if (s>best){best=s;winner=n;}
    bool cm = (n==0) || (scraw[base+(size_t)n*HW_] > 0.5f);
    if (cm) cbits |= 1<<n;
  }
  int ob = ((cbits>>winner)&1) ? (1<<winner) : 0;
  omask[(size_t)b*HW_+p] = ob | (cbits<<8);
}

// ---------- K7: 3x3 dilation, final mask, effective-rate count ----------
__global__ __launch_bounds__(256) void k_final(
  const int* __restrict__ omask, int* __restrict__ fmask, int* __restrict__ counter)
{
  int w=threadIdx.x,h=blockIdx.x,b=blockIdx.y;
  int p=h*W_+w;
  const int* om = omask + (size_t)b*HW_;
  int ow=0;
  #pragma unroll
  for (int dy=-1;dy<=1;++dy){
    int y=h+dy; if (y<0||y>=H_) continue;
    #pragma unroll
    for (int dx=-1;dx<=1;++dx){
      int x=w+dx; if (x<0||x>=W_) continue;
      ow |= om[y*W_+x];
    }
  }
  int cbits=(om[p]>>8)&31;
  int fin = ow & cbits & 31;
  fmask[(size_t)b*HW_+p]=fin;
  int cn = __popc(fin & 30);
  for (int off=32;off;off>>=1) cn += __shfl_down(cn,off);
  if ((threadIdx.x&63)==0) atomicAdd(counter, cn);
}

// ---------- K8: masked-max warped output + effective rate ----------
__global__ __launch_bounds__(256, 2) void k_out(
  const float* __restrict__ x, const float* __restrict__ nam,
  const int* __restrict__ fmask, const int* __restrict__ counter,
  float* __restrict__ out, int out_size)
{
  int w=threadIdx.x, h=blockIdx.x, b=blockIdx.y;
  int p=h*W_+w;
  int fin = fmask[(size_t)b*HW_+p] & 31;
  float init = (__popc(fin)<NA) ? 0.f : -__builtin_inff();
  Taps tp[NA];
  #pragma unroll
  for (int n=0;n<NA;++n) tp[n] = make_taps(nam + (size_t)(b*NA*NA+n)*6, h, w);
  #pragma unroll 1
  for (int cb=0; cb<NC/16; ++cb){
    float m[16];
    #pragma unroll
    for (int c=0;c<16;++c) m[c]=init;
    #pragma unroll
    for (int n=0;n<NA;++n){
      if (!((fin>>n)&1)) continue;
      const float* pc = x + ((size_t)(b*NA+n)*NC + cb*16)*HW_;
      float a00[16],a01[16],a10[16],a11[16];
      #pragma unroll
      for (int c=0;c<16;++c){
        a00[c]=pc[tp[n].o00]; a01[c]=pc[tp[n].o01]; a10[c]=pc[tp[n].o10]; a11[c]=pc[tp[n].o11];
        pc += HW_;
      }
      #pragma unroll
      for (int c=0;c<16;++c){
        float v = tp[n].w00*a00[c] + tp[n].w01*a01[c] + tp[n].w10*a10[c] + tp[n].w11*a11[c];
        m[c] = fmaxf(m[c], v);
      }
    }
    #pragma unroll
    for (int c=0;c<16;++c)
      out[(((size_t)b*NC + cb*16 + c)*H_+h)*W_+w] = m[c];
  }
  if (b==0 && h==0 && w==0)
    out[out_size-1] = (float)(*counter) * (1.0f/524288.0f);  // /(B*(N-1)*H*W)
}

extern "C" void kernel_launch(void* const* d_in, const int* in_sizes, int n_in,
                              void* d_out, int out_size, void* d_ws, size_t ws_size,
                              hipStream_t stream) {
  (void)in_sizes; (void)n_in; (void)ws_size;
  const float* x   = (const float*)d_in[0];
  const float* psm = (const float*)d_in[1];
  const float* nam = (const float*)d_in[3];
  float* out = (float*)d_out;

  float* ws     = (float*)d_ws;
  float* vis    = ws;                         // 20*HW
  float* scraw  = vis    + (size_t)NIMG*HW_;  // 20*HW
  float* sfull  = scraw  + (size_t)NIMG*HW_;  // 20*HW
  float* energy = sfull  + (size_t)NIMG*HW_;  // 20*HW
  float* ppre   = energy + (size_t)NIMG*HW_;  // 4*HW
  float* statsE = ppre   + (size_t)NB*HW_;    // 20*16
  float* statsC = statsE + NIMG*16;           // 20*16
  float* statsP = statsC + NIMG*16;           // 4*16
  float* params = statsP + NB*16;             // 4*32
  int*   omask  = (int*)(params + NB*32);     // 4*HW
  int*   fmask  = omask + (size_t)NB*HW_;     // 4*HW
  int*   counter= fmask + (size_t)NB*HW_;     // 1 (+ NIMG vis-counts)
  int*   cntv   = counter + 1;                // 20

  hipLaunchKernelGGL(k_init, dim3(1), dim3(64), 0, stream, counter);
  hipLaunchKernelGGL(k_warp_stats, dim3(W_/TW, H_/TH, NIMG), dim3(256), 0, stream,
                     x, psm, nam, vis, scraw, sfull, energy, cntv);
  hipLaunchKernelGGL(k_select, dim3(192), dim3(OS_T), 0, stream,
                     energy, scraw, ppre, vis, cntv, statsE, statsC, statsP, 0);
  hipLaunchKernelGGL(k_params, dim3(1), dim3(64), 0, stream, statsE, statsC, params);
  hipLaunchKernelGGL(k_ppre, dim3(H_,NB), dim3(W_), 0, stream,
                     vis, scraw, energy, params, ppre);
  hipLaunchKernelGGL(k_select, dim3(16), dim3(OS_T), 0, stream,
                     energy, scraw, ppre, vis, cntv, statsE, statsC, statsP, 1);
  hipLaunchKernelGGL(k_owner, dim3(H_,NB), dim3(W_), 0, stream,
                     vis, scraw, sfull, ppre, statsP, omask);
  hipLaunchKernelGGL(k_final, dim3(H_,NB), dim3(W_), 0, stream, omask, fmask, counter);
  hipLaunchKernelGGL(k_out, dim3(H_,NB), dim3(W_), 0, stream,
                     x, nam, fmask, counter, out, out_size);
}